// Round 2
// baseline (1156.077 us; speedup 1.0000x reference)
//
#include <hip/hip_runtime.h>
#include <cmath>

typedef __bf16 bf16;
typedef __bf16 bf16x8 __attribute__((ext_vector_type(8)));
typedef float f32x4 __attribute__((ext_vector_type(4)));

// B=16, C_IN=256, H=W=64, C_OUT=256, 3x3, stride 1, pad 1, CURV=1

__device__ inline void gload16(const void* g, void* l) {
    __builtin_amdgcn_global_load_lds(
        (const __attribute__((address_space(1))) unsigned int*)g,
        (__attribute__((address_space(3))) unsigned int*)l, 16, 0, 0);
}

// ---------------------------------------------------------------------------
// Weight transform: z[k=c*9+tap][co] (fp32) -> zt2[tap][kstep][co][32] (bf16)
// kstep = 32-channel K-step index (8 per tap). B-frag loads become contiguous.
__global__ void k_prep_zt(const float* __restrict__ z, bf16* __restrict__ zt2) {
    int blk = blockIdx.x;              // 72 = tap*8 + kstep
    int tap = blk >> 3, kstep = blk & 7;
    int co = threadIdx.x;
    bf16* o = zt2 + ((size_t)blk * 256 + co) * 32;
#pragma unroll
    for (int cj8 = 0; cj8 < 4; ++cj8) {
        bf16x8 pk;
#pragma unroll
        for (int e = 0; e < 8; ++e) {
            int c = kstep * 32 + cj8 * 8 + e;
            pk[e] = (bf16)z[(size_t)(c * 9 + tap) * 256 + co];
        }
        *(bf16x8*)(o + cj8 * 8) = pk;
    }
}

// Column constants: zn[co]=max(||z[:,co]||,eps), ch=cosh(2r), sh=sinh(2r)
__global__ void k_prep_cols(const float* __restrict__ z, const float* __restrict__ r,
                            float* __restrict__ zn, float* __restrict__ ch,
                            float* __restrict__ sh) {
    __shared__ float red[256];
    int co = blockIdx.x, t = threadIdx.x;
    float s = 0.f;
    for (int i = 0; i < 9; ++i) {
        float v = z[(size_t)(i * 256 + t) * 256 + co];
        s += v * v;
    }
    red[t] = s;
    __syncthreads();
    for (int off = 128; off >= 1; off >>= 1) {
        if (t < off) red[t] += red[t + off];
        __syncthreads();
    }
    if (t == 0) {
        zn[co] = fmaxf(sqrtf(red[0]), 1e-15f);
        float tc = 2.f * r[co];
        ch[co] = coshf(tc);
        sh[co] = sinhf(tc);
    }
}

// ---------------------------------------------------------------------------
// logmap0 * beta-ratio, transpose [B,C,HW] -> vt[B,HW,C] bf16, and per-pixel
// sq = sum_c v^2 (fp32).
__global__ void k_logmap(const float* __restrict__ x, unsigned int* __restrict__ vt_u,
                         float* __restrict__ sq, float Rbeta) {
    __shared__ float tile[256][33];
    __shared__ float red[8][32];
    __shared__ float afac[32];
    int tid = threadIdx.x;
    int blk = blockIdx.x;
    int b = blk >> 7;
    int pix0 = (blk & 127) << 5;

    for (int it = 0; it < 32; ++it) {
        int c = it * 8 + (tid >> 5);
        int p = tid & 31;
        tile[c][p] = x[((size_t)b * 256 + c) * 4096 + pix0 + p];
    }
    __syncthreads();

    {
        int part = tid >> 5, p = tid & 31;
        float s = 0.f;
        for (int i = 0; i < 32; ++i) {
            float v = tile[part * 32 + i][p];
            s += v * v;
        }
        red[part][p] = s;
    }
    __syncthreads();
    if (tid < 32) {
        float n2 = 0.f;
        for (int i = 0; i < 8; ++i) n2 += red[i][tid];
        float n = sqrtf(n2);
        float nc = fmaxf(n, 1e-15f);
        float a = atanhf(fminf(nc, 0.9999999f)) / nc * Rbeta;
        afac[tid] = a;
        sq[(size_t)b * 4096 + pix0 + tid] = a * a * n2;
    }
    __syncthreads();

    for (int it = 0; it < 16; ++it) {
        int idx = it * 256 + tid;
        int p = idx >> 7;
        int cp = idx & 127;
        float a = afac[p];
        float v0 = a * tile[2 * cp][p];
        float v1 = a * tile[2 * cp + 1][p];
        union { bf16 h[2]; unsigned int u; } pk;
        pk.h[0] = (bf16)v0;
        pk.h[1] = (bf16)v1;
        vt_u[((size_t)b * 4096 + pix0 + p) * 128 + cp] = pk.u;
    }
}

// 3x3 zero-padded box sum of sq -> nusq
__global__ void k_boxsum(const float* __restrict__ sq, float* __restrict__ nusq) {
    int idx = blockIdx.x * 256 + threadIdx.x;
    int b = idx >> 12, hw = idx & 4095, h = hw >> 6, w = hw & 63;
    const float* s = sq + ((size_t)b << 12);
    float acc = 0.f;
    for (int dh = -1; dh <= 1; ++dh) {
        int hh = h + dh;
        if ((unsigned)hh >= 64u) continue;
        for (int dw = -1; dw <= 1; ++dw) {
            int ww = w + dw;
            if ((unsigned)ww >= 64u) continue;
            acc += s[hh * 64 + ww];
        }
    }
    nusq[idx] = acc;
}

// ---------------------------------------------------------------------------
// Fused implicit-GEMM conv + hyperbolic FC epilogue, LDS-staged.
// Block: 2 image rows (128 px) x 256 co, 8 waves (wm in {0,1} -> row, wn in
// {0..3} -> 64-co quarter). Per-wave tile 64 px x 64 co: acc[4][4].
// K loop: 4 chunks of 64 channels; A tile (4 rows x 64 px x 64 ch, XOR-
// swizzled) staged via global_load_lds; all 9 taps read from it.
__launch_bounds__(512, 4)
__global__ void k_hconv(const bf16* __restrict__ vt, const bf16* __restrict__ zt2,
                        const float* __restrict__ nusq,
                        const float* __restrict__ znp, const float* __restrict__ chp,
                        const float* __restrict__ shp, float* __restrict__ out) {
    __shared__ bf16 As[16384];            // 32 KB: [r4][px64][ch64], swizzled
    __shared__ float s_lds[128], lam_lds[128];
    __shared__ float red[128][4];

    int tid = threadIdx.x;
    int bh = blockIdx.x;                  // b*32 + rowpair
    int b = bh >> 5, h0 = (bh & 31) << 1;

    if (tid < 128) {
        int h = h0 + (tid >> 6), w = tid & 63;
        float q = nusq[((size_t)b << 12) + h * 64 + w];
        float ncl = fmaxf(sqrtf(q), 1e-15f);
        float t = tanhf(ncl);
        float s = t / ncl;                // expmap scale
        s_lds[tid] = s;
        lam_lds[tid] = 2.f / (1.f - s * s * q);
    }

    int wave = tid >> 6, lane = tid & 63;
    int wn = wave & 3, wm = wave >> 2;
    int lrow = lane & 15, lk = lane >> 4;

    f32x4 acc[4][4];
#pragma unroll
    for (int m = 0; m < 4; ++m)
#pragma unroll
        for (int n = 0; n < 4; ++n) acc[m][n] = (f32x4){0.f, 0.f, 0.f, 0.f};

    bf16x8 zf;
#pragma unroll
    for (int e = 0; e < 8; ++e) zf[e] = (bf16)0.0f;

    const bf16* vb = vt + (((size_t)b) << 12) * 256;
    int ldsb = wave * 1024;

    for (int cc = 0; cc < 4; ++cc) {
        __syncthreads();                  // prior reads of As complete
        // ---- stage A chunk: rows h0-1..h0+2, 64 px, ch [cc*64, cc*64+64) ----
#pragma unroll
        for (int it = 0; it < 4; ++it) {
            int o = it * 8192 + tid * 16; // linear byte offset in As
            int r = o >> 13;
            int rem = o & 8191;
            int px = rem >> 7;
            int q = (rem >> 4) & 7;
            int qs = q ^ (px & 7);        // pre-swizzled source chunk
            int hr = h0 - 1 + r;
            hr = hr < 0 ? 0 : (hr > 63 ? 63 : hr);   // clamped rows are dead
            const bf16* g = vb + (((size_t)(hr * 64 + px)) << 8) + cc * 64 + qs * 8;
            gload16(g, (char*)As + it * 8192 + ldsb);
        }
        asm volatile("s_waitcnt vmcnt(0)" ::: "memory");
        __syncthreads();                  // staged data visible

#pragma unroll
        for (int tap = 0; tap < 9; ++tap) {
            const int dh = tap / 3 - 1, dw = tap % 3 - 1;
            int hh = h0 + wm + dh;
            if ((unsigned)hh >= 64u) continue;       // wave-uniform skip
            int r = wm + dh + 1;
#pragma unroll
            for (int ks = 0; ks < 2; ++ks) {
                bf16x8 a[4];
#pragma unroll
                for (int m = 0; m < 4; ++m) {
                    int pxs = m * 16 + lrow + dw;
                    bool ok = (unsigned)pxs < 64u;
                    int pxc = ok ? pxs : 0;
                    int off = r * 8192 + pxc * 128 +
                              ((ks * 64 + lk * 16) ^ ((pxc & 7) << 4));
                    bf16x8 av = *(const bf16x8*)((const char*)As + off);
                    a[m] = ok ? av : zf;
                }
#pragma unroll
                for (int n = 0; n < 4; ++n) {
                    const bf16* bp = zt2 +
                        (((size_t)(tap * 8 + cc * 2 + ks) * 256) +
                         wn * 64 + n * 16 + lrow) * 32 + lk * 8;
                    bf16x8 bb = *(const bf16x8*)bp;
#pragma unroll
                    for (int m = 0; m < 4; ++m)
                        acc[m][n] = __builtin_amdgcn_mfma_f32_16x16x32_bf16(
                            a[m], bb, acc[m][n], 0, 0, 0);
                }
            }
        }
    }

    // ---------------- epilogue ----------------
    float znv[4], chv[4], shv[4];
#pragma unroll
    for (int n = 0; n < 4; ++n) {
        int co = wn * 64 + n * 16 + lrow;
        znv[n] = znp[co];
        chv[n] = chp[co];
        shv[n] = shp[co];
    }

#pragma unroll
    for (int m = 0; m < 4; ++m) {
#pragma unroll
        for (int r = 0; r < 4; ++r) {
            int wp = wm * 64 + m * 16 + 4 * lk + r;   // block-local pixel slot
            float s = s_lds[wp], lam = lam_lds[wp];
            float psum = 0.f;
#pragma unroll
            for (int n = 0; n < 4; ++n) {
                float xz = s * acc[m][n][r];
                float inner = lam * xz / znv[n] * chv[n] - (lam - 1.f) * shv[n];
                float vhp = 2.f * znv[n] * asinhf(inner);
                float w = sinhf(vhp);
                acc[m][n][r] = w;
                psum += w * w;
            }
            psum += __shfl_xor(psum, 1);
            psum += __shfl_xor(psum, 2);
            psum += __shfl_xor(psum, 4);
            psum += __shfl_xor(psum, 8);
            if (lrow == 0) red[wp][wn] = psum;
        }
    }
    __syncthreads();

    float* ob = out + (size_t)b * 256 * 4096 + (h0 + wm) * 64;
#pragma unroll
    for (int m = 0; m < 4; ++m) {
#pragma unroll
        for (int n = 0; n < 4; ++n) {
            int co = wn * 64 + n * 16 + lrow;
            f32x4 o;
#pragma unroll
            for (int r = 0; r < 4; ++r) {
                int wp = wm * 64 + m * 16 + 4 * lk + r;
                float tot = red[wp][0] + red[wp][1] + red[wp][2] + red[wp][3];
                o[r] = acc[m][n][r] / (1.f + sqrtf(1.f + tot));
            }
            *(f32x4*)(ob + (size_t)co * 4096 + m * 16 + 4 * lk) = o;
        }
    }
}

// ---------------------------------------------------------------------------
extern "C" void kernel_launch(void* const* d_in, const int* in_sizes, int n_in,
                              void* d_out, int out_size, void* d_ws, size_t ws_size,
                              hipStream_t stream) {
    const float* x = (const float*)d_in[0];   // [16,256,64,64]
    const float* z = (const float*)d_in[1];   // [2304,256]
    const float* r = (const float*)d_in[2];   // [256]
    float* out = (float*)d_out;               // [16,256,64,64]

    char* ws = (char*)d_ws;
    bf16* vt = (bf16*)ws;                         // 33,554,432 B
    float* sq = (float*)(ws + 33554432);          //    262,144 B
    float* nusq = (float*)(ws + 33816576);        //    262,144 B
    bf16* zt2 = (bf16*)(ws + 34078720);           //  1,179,648 B
    float* zn = (float*)(ws + 35258368);
    float* ch = (float*)(ws + 35259392);
    float* sh = (float*)(ws + 35260416);
    if (ws_size < 35261440) return;

    double bni = lgamma(128.0) + lgamma(0.5) - lgamma(128.5);
    double bn = lgamma(1152.0) + lgamma(0.5) - lgamma(1152.5);
    float Rbeta = (float)exp(bn - bni);

    k_prep_zt<<<72, 256, 0, stream>>>(z, zt2);
    k_prep_cols<<<256, 256, 0, stream>>>(z, r, zn, ch, sh);
    k_logmap<<<2048, 256, 0, stream>>>(x, (unsigned int*)vt, sq, Rbeta);
    k_boxsum<<<256, 256, 0, stream>>>(sq, nusq);
    k_hconv<<<512, 512, 0, stream>>>(vt, zt2, nusq, zn, ch, sh, out);
}

// Round 3
// 902.863 us; speedup vs baseline: 1.2805x; 1.2805x over previous
//
#include <hip/hip_runtime.h>
#include <cmath>

typedef __bf16 bf16;
typedef __bf16 bf16x8 __attribute__((ext_vector_type(8)));
typedef float f32x4 __attribute__((ext_vector_type(4)));

// B=16, C_IN=256, H=W=64, C_OUT=256, 3x3, stride 1, pad 1, CURV=1

__device__ inline void gload16(const void* g, void* l) {
    __builtin_amdgcn_global_load_lds(
        (const __attribute__((address_space(1))) unsigned int*)g,
        (__attribute__((address_space(3))) unsigned int*)l, 16, 0, 0);
}

// ---------------------------------------------------------------------------
// Weight transform: z[k=c*9+tap][co] (fp32) -> zt2[tap][kstep][co][32] (bf16)
__global__ void k_prep_zt(const float* __restrict__ z, bf16* __restrict__ zt2) {
    int blk = blockIdx.x;              // 72 = tap*8 + kstep
    int tap = blk >> 3, kstep = blk & 7;
    int co = threadIdx.x;
    bf16* o = zt2 + ((size_t)blk * 256 + co) * 32;
#pragma unroll
    for (int cj8 = 0; cj8 < 4; ++cj8) {
        bf16x8 pk;
#pragma unroll
        for (int e = 0; e < 8; ++e) {
            int c = kstep * 32 + cj8 * 8 + e;
            pk[e] = (bf16)z[(size_t)(c * 9 + tap) * 256 + co];
        }
        *(bf16x8*)(o + cj8 * 8) = pk;
    }
}

// Column constants
__global__ void k_prep_cols(const float* __restrict__ z, const float* __restrict__ r,
                            float* __restrict__ zn, float* __restrict__ ch,
                            float* __restrict__ sh) {
    __shared__ float red[256];
    int co = blockIdx.x, t = threadIdx.x;
    float s = 0.f;
    for (int i = 0; i < 9; ++i) {
        float v = z[(size_t)(i * 256 + t) * 256 + co];
        s += v * v;
    }
    red[t] = s;
    __syncthreads();
    for (int off = 128; off >= 1; off >>= 1) {
        if (t < off) red[t] += red[t + off];
        __syncthreads();
    }
    if (t == 0) {
        zn[co] = fmaxf(sqrtf(red[0]), 1e-15f);
        float tc = 2.f * r[co];
        ch[co] = coshf(tc);
        sh[co] = sinhf(tc);
    }
}

// ---------------------------------------------------------------------------
__global__ void k_logmap(const float* __restrict__ x, unsigned int* __restrict__ vt_u,
                         float* __restrict__ sq, float Rbeta) {
    __shared__ float tile[256][33];
    __shared__ float red[8][32];
    __shared__ float afac[32];
    int tid = threadIdx.x;
    int blk = blockIdx.x;
    int b = blk >> 7;
    int pix0 = (blk & 127) << 5;

    for (int it = 0; it < 32; ++it) {
        int c = it * 8 + (tid >> 5);
        int p = tid & 31;
        tile[c][p] = x[((size_t)b * 256 + c) * 4096 + pix0 + p];
    }
    __syncthreads();

    {
        int part = tid >> 5, p = tid & 31;
        float s = 0.f;
        for (int i = 0; i < 32; ++i) {
            float v = tile[part * 32 + i][p];
            s += v * v;
        }
        red[part][p] = s;
    }
    __syncthreads();
    if (tid < 32) {
        float n2 = 0.f;
        for (int i = 0; i < 8; ++i) n2 += red[i][tid];
        float n = sqrtf(n2);
        float nc = fmaxf(n, 1e-15f);
        float a = atanhf(fminf(nc, 0.9999999f)) / nc * Rbeta;
        afac[tid] = a;
        sq[(size_t)b * 4096 + pix0 + tid] = a * a * n2;
    }
    __syncthreads();

    for (int it = 0; it < 16; ++it) {
        int idx = it * 256 + tid;
        int p = idx >> 7;
        int cp = idx & 127;
        float a = afac[p];
        float v0 = a * tile[2 * cp][p];
        float v1 = a * tile[2 * cp + 1][p];
        union { bf16 h[2]; unsigned int u; } pk;
        pk.h[0] = (bf16)v0;
        pk.h[1] = (bf16)v1;
        vt_u[((size_t)b * 4096 + pix0 + p) * 128 + cp] = pk.u;
    }
}

__global__ void k_boxsum(const float* __restrict__ sq, float* __restrict__ nusq) {
    int idx = blockIdx.x * 256 + threadIdx.x;
    int b = idx >> 12, hw = idx & 4095, h = hw >> 6, w = hw & 63;
    const float* s = sq + ((size_t)b << 12);
    float acc = 0.f;
    for (int dh = -1; dh <= 1; ++dh) {
        int hh = h + dh;
        if ((unsigned)hh >= 64u) continue;
        for (int dw = -1; dw <= 1; ++dw) {
            int ww = w + dw;
            if ((unsigned)ww >= 64u) continue;
            acc += s[hh * 64 + ww];
        }
    }
    nusq[idx] = acc;
}

// ---------------------------------------------------------------------------
// Fused implicit-GEMM conv + hyperbolic FC epilogue.
// Block: 2 image rows (128 px) x 256 co, 8 waves (wm row, wn co-quarter),
// per-wave tile 64 px x 64 co (acc[4][4]). K: 4 chunks of 64 ch, A tile
// double-buffered in LDS (2-phase, counted vmcnt, raw barriers).
__launch_bounds__(512, 2)
__global__ void k_hconv(const bf16* __restrict__ vt, const bf16* __restrict__ zt2,
                        const float* __restrict__ nusq,
                        const float* __restrict__ znp, const float* __restrict__ chp,
                        const float* __restrict__ shp, float* __restrict__ out) {
    __shared__ __align__(1024) char Asb[65536];   // 2 x 32KB A buffers
    __shared__ float s_lds[128], lam_lds[128];
    __shared__ float red[128][4];

    int tid = threadIdx.x;
    int bh = blockIdx.x;                  // b*32 + rowpair
    int b = bh >> 5, h0 = (bh & 31) << 1;

    if (tid < 128) {
        int h = h0 + (tid >> 6), w = tid & 63;
        float q = nusq[((size_t)b << 12) + h * 64 + w];
        float ncl = fmaxf(sqrtf(q), 1e-15f);
        float t = tanhf(ncl);
        float s = t / ncl;
        s_lds[tid] = s;
        lam_lds[tid] = 2.f / (1.f - s * s * q);
    }

    int wave = tid >> 6, lane = tid & 63;
    int wn = wave & 3, wm = wave >> 2;
    int lrow = lane & 15, lk = lane >> 4;

    f32x4 acc[4][4];
#pragma unroll
    for (int m = 0; m < 4; ++m)
#pragma unroll
        for (int n = 0; n < 4; ++n) acc[m][n] = (f32x4){0.f, 0.f, 0.f, 0.f};

    bf16x8 zf;
#pragma unroll
    for (int e = 0; e < 8; ++e) zf[e] = (bf16)0.0f;

    const bf16* vb = vt + (((size_t)b) << 12) * 256;
    int ldsb = wave * 1024;               // lane-linear dest within stage slice

    // stage chunk cc of A (4 rows x 64 px x 64 ch, XOR-swizzled source)
    auto stage = [&](int buf, int cc) {
#pragma unroll
        for (int it = 0; it < 4; ++it) {
            int o = it * 8192 + tid * 16;
            int r = o >> 13;
            int rem = o & 8191;
            int px = rem >> 7;
            int q = (rem >> 4) & 7;
            int qs = q ^ (px & 7);
            int hr = h0 - 1 + r;
            hr = hr < 0 ? 0 : (hr > 63 ? 63 : hr);
            const bf16* g = vb + (((size_t)(hr * 64 + px)) << 8) + cc * 64 + qs * 8;
            gload16(g, Asb + buf * 32768 + it * 8192 + ldsb);
        }
    };

    stage(0, 0);                          // prologue
    __syncthreads();                      // s_lds/lam_lds visible (also syncs)

    for (int cc = 0; cc < 4; ++cc) {
        if (cc < 3) {
            stage((cc + 1) & 1, cc + 1);  // issue next chunk into other buffer
            asm volatile("s_waitcnt vmcnt(4)" ::: "memory");  // cur chunk done
        } else {
            asm volatile("s_waitcnt vmcnt(0)" ::: "memory");
        }
        asm volatile("s_barrier" ::: "memory");   // staged data visible

        const char* Ab = Asb + ((cc & 1) << 15);
#pragma unroll
        for (int tap = 0; tap < 9; ++tap) {
            const int dh = tap / 3 - 1, dw = tap % 3 - 1;
            int hh = h0 + wm + dh;
            if ((unsigned)hh >= 64u) continue;      // wave-uniform skip
            int r = wm + dh + 1;
#pragma unroll
            for (int ks = 0; ks < 2; ++ks) {
                bf16x8 a[4];
#pragma unroll
                for (int m = 0; m < 4; ++m) {
                    int pxs = m * 16 + lrow + dw;
                    bool ok = (unsigned)pxs < 64u;
                    int pxc = ok ? pxs : 0;
                    int off = r * 8192 + pxc * 128 +
                              ((ks * 64 + lk * 16) ^ ((pxc & 7) << 4));
                    bf16x8 av = *(const bf16x8*)(Ab + off);
                    a[m] = ok ? av : zf;
                }
#pragma unroll
                for (int n = 0; n < 4; ++n) {
                    const bf16* bp = zt2 +
                        (((size_t)(tap * 8 + cc * 2 + ks) * 256) +
                         wn * 64 + n * 16 + lrow) * 32 + lk * 8;
                    bf16x8 bb = *(const bf16x8*)bp;
#pragma unroll
                    for (int m = 0; m < 4; ++m)
                        acc[m][n] = __builtin_amdgcn_mfma_f32_16x16x32_bf16(
                            a[m], bb, acc[m][n], 0, 0, 0);
                }
            }
        }
        asm volatile("s_barrier" ::: "memory");   // all reads done before restage
    }

    // ---------------- epilogue ----------------
    float znv[4], chv[4], shv[4];
#pragma unroll
    for (int n = 0; n < 4; ++n) {
        int co = wn * 64 + n * 16 + lrow;
        znv[n] = znp[co];
        chv[n] = chp[co];
        shv[n] = shp[co];
    }

#pragma unroll
    for (int m = 0; m < 4; ++m) {
#pragma unroll
        for (int r = 0; r < 4; ++r) {
            int wp = wm * 64 + m * 16 + 4 * lk + r;
            float s = s_lds[wp], lam = lam_lds[wp];
            float psum = 0.f;
#pragma unroll
            for (int n = 0; n < 4; ++n) {
                float xz = s * acc[m][n][r];
                float inner = lam * xz / znv[n] * chv[n] - (lam - 1.f) * shv[n];
                float vhp = 2.f * znv[n] * asinhf(inner);
                float w = sinhf(vhp);
                acc[m][n][r] = w;
                psum += w * w;
            }
            psum += __shfl_xor(psum, 1);
            psum += __shfl_xor(psum, 2);
            psum += __shfl_xor(psum, 4);
            psum += __shfl_xor(psum, 8);
            if (lrow == 0) red[wp][wn] = psum;
        }
    }
    __syncthreads();

    float* ob = out + (size_t)b * 256 * 4096 + (h0 + wm) * 64;
#pragma unroll
    for (int m = 0; m < 4; ++m) {
#pragma unroll
        for (int n = 0; n < 4; ++n) {
            int co = wn * 64 + n * 16 + lrow;
            f32x4 o;
#pragma unroll
            for (int r = 0; r < 4; ++r) {
                int wp = wm * 64 + m * 16 + 4 * lk + r;
                float tot = red[wp][0] + red[wp][1] + red[wp][2] + red[wp][3];
                o[r] = acc[m][n][r] / (1.f + sqrtf(1.f + tot));
            }
            *(f32x4*)(ob + (size_t)co * 4096 + m * 16 + 4 * lk) = o;
        }
    }
}

// ---------------------------------------------------------------------------
extern "C" void kernel_launch(void* const* d_in, const int* in_sizes, int n_in,
                              void* d_out, int out_size, void* d_ws, size_t ws_size,
                              hipStream_t stream) {
    const float* x = (const float*)d_in[0];   // [16,256,64,64]
    const float* z = (const float*)d_in[1];   // [2304,256]
    const float* r = (const float*)d_in[2];   // [256]
    float* out = (float*)d_out;               // [16,256,64,64]

    char* ws = (char*)d_ws;
    bf16* vt = (bf16*)ws;                         // 33,554,432 B
    float* sq = (float*)(ws + 33554432);
    float* nusq = (float*)(ws + 33816576);
    bf16* zt2 = (bf16*)(ws + 34078720);
    float* zn = (float*)(ws + 35258368);
    float* ch = (float*)(ws + 35259392);
    float* sh = (float*)(ws + 35260416);
    if (ws_size < 35261440) return;

    double bni = lgamma(128.0) + lgamma(0.5) - lgamma(128.5);
    double bn = lgamma(1152.0) + lgamma(0.5) - lgamma(1152.5);
    float Rbeta = (float)exp(bn - bni);

    k_prep_zt<<<72, 256, 0, stream>>>(z, zt2);
    k_prep_cols<<<256, 256, 0, stream>>>(z, r, zn, ch, sh);
    k_logmap<<<2048, 256, 0, stream>>>(x, (unsigned int*)vt, sq, Rbeta);
    k_boxsum<<<256, 256, 0, stream>>>(sq, nusq);
    k_hconv<<<512, 512, 0, stream>>>(vt, zt2, nusq, zn, ch, sh, out);
}

// Round 4
// 901.399 us; speedup vs baseline: 1.2825x; 1.0016x over previous
//
#include <hip/hip_runtime.h>
#include <cmath>

typedef __bf16 bf16;
typedef __bf16 bf16x8 __attribute__((ext_vector_type(8)));
typedef float f32x4 __attribute__((ext_vector_type(4)));

// B=16, C_IN=256, H=W=64, C_OUT=256, 3x3, stride 1, pad 1, CURV=1

__device__ inline void gload16(const void* g, void* l) {
    __builtin_amdgcn_global_load_lds(
        (const __attribute__((address_space(1))) unsigned int*)g,
        (__attribute__((address_space(3))) unsigned int*)l, 16, 0, 0);
}

// ---------------------------------------------------------------------------
// Weight transform: z[k=c*9+tap][co] (fp32) -> zt2[tap][kstep][co][32] (bf16)
__global__ void k_prep_zt(const float* __restrict__ z, bf16* __restrict__ zt2) {
    int blk = blockIdx.x;              // 72 = tap*8 + kstep
    int tap = blk >> 3, kstep = blk & 7;
    int co = threadIdx.x;
    bf16* o = zt2 + ((size_t)blk * 256 + co) * 32;
#pragma unroll
    for (int cj8 = 0; cj8 < 4; ++cj8) {
        bf16x8 pk;
#pragma unroll
        for (int e = 0; e < 8; ++e) {
            int c = kstep * 32 + cj8 * 8 + e;
            pk[e] = (bf16)z[(size_t)(c * 9 + tap) * 256 + co];
        }
        *(bf16x8*)(o + cj8 * 8) = pk;
    }
}

// Column constants
__global__ void k_prep_cols(const float* __restrict__ z, const float* __restrict__ r,
                            float* __restrict__ zn, float* __restrict__ ch,
                            float* __restrict__ sh) {
    __shared__ float red[256];
    int co = blockIdx.x, t = threadIdx.x;
    float s = 0.f;
    for (int i = 0; i < 9; ++i) {
        float v = z[(size_t)(i * 256 + t) * 256 + co];
        s += v * v;
    }
    red[t] = s;
    __syncthreads();
    for (int off = 128; off >= 1; off >>= 1) {
        if (t < off) red[t] += red[t + off];
        __syncthreads();
    }
    if (t == 0) {
        zn[co] = fmaxf(sqrtf(red[0]), 1e-15f);
        float tc = 2.f * r[co];
        ch[co] = coshf(tc);
        sh[co] = sinhf(tc);
    }
}

// ---------------------------------------------------------------------------
__global__ void k_logmap(const float* __restrict__ x, unsigned int* __restrict__ vt_u,
                         float* __restrict__ sq, float Rbeta) {
    __shared__ float tile[256][33];
    __shared__ float red[8][32];
    __shared__ float afac[32];
    int tid = threadIdx.x;
    int blk = blockIdx.x;
    int b = blk >> 7;
    int pix0 = (blk & 127) << 5;

    for (int it = 0; it < 32; ++it) {
        int c = it * 8 + (tid >> 5);
        int p = tid & 31;
        tile[c][p] = x[((size_t)b * 256 + c) * 4096 + pix0 + p];
    }
    __syncthreads();

    {
        int part = tid >> 5, p = tid & 31;
        float s = 0.f;
        for (int i = 0; i < 32; ++i) {
            float v = tile[part * 32 + i][p];
            s += v * v;
        }
        red[part][p] = s;
    }
    __syncthreads();
    if (tid < 32) {
        float n2 = 0.f;
        for (int i = 0; i < 8; ++i) n2 += red[i][tid];
        float n = sqrtf(n2);
        float nc = fmaxf(n, 1e-15f);
        float a = atanhf(fminf(nc, 0.9999999f)) / nc * Rbeta;
        afac[tid] = a;
        sq[(size_t)b * 4096 + pix0 + tid] = a * a * n2;
    }
    __syncthreads();

    for (int it = 0; it < 16; ++it) {
        int idx = it * 256 + tid;
        int p = idx >> 7;
        int cp = idx & 127;
        float a = afac[p];
        float v0 = a * tile[2 * cp][p];
        float v1 = a * tile[2 * cp + 1][p];
        union { bf16 h[2]; unsigned int u; } pk;
        pk.h[0] = (bf16)v0;
        pk.h[1] = (bf16)v1;
        vt_u[((size_t)b * 4096 + pix0 + p) * 128 + cp] = pk.u;
    }
}

__global__ void k_boxsum(const float* __restrict__ sq, float* __restrict__ nusq) {
    int idx = blockIdx.x * 256 + threadIdx.x;
    int b = idx >> 12, hw = idx & 4095, h = hw >> 6, w = hw & 63;
    const float* s = sq + ((size_t)b << 12);
    float acc = 0.f;
    for (int dh = -1; dh <= 1; ++dh) {
        int hh = h + dh;
        if ((unsigned)hh >= 64u) continue;
        for (int dw = -1; dw <= 1; ++dw) {
            int ww = w + dw;
            if ((unsigned)ww >= 64u) continue;
            acc += s[hh * 64 + ww];
        }
    }
    nusq[idx] = acc;
}

// ---------------------------------------------------------------------------
// Fused implicit-GEMM conv + hyperbolic FC epilogue.
// Block: 2 image rows (128 px) x 256 co, 8 waves (wm row, wn co-quarter),
// per-wave tile 64 px x 64 co (acc[4][4]). K: 4 chunks of 64 ch, A tile
// double-buffered in LDS (2-phase, counted vmcnt, raw barriers).
// launch_bounds min-waves=1: do NOT cap registers (cap 128 spilled acc ->
// 4.3 GB scratch writes in rounds 2-3).
__launch_bounds__(512, 1)
__global__ void k_hconv(const bf16* __restrict__ vt, const bf16* __restrict__ zt2,
                        const float* __restrict__ nusq,
                        const float* __restrict__ znp, const float* __restrict__ chp,
                        const float* __restrict__ shp, float* __restrict__ out) {
    __shared__ __align__(1024) char Asb[65536];   // 2 x 32KB A buffers
    __shared__ float s_lds[128], lam_lds[128];
    __shared__ float red[128][4];

    int tid = threadIdx.x;
    int bh = blockIdx.x;                  // b*32 + rowpair
    int b = bh >> 5, h0 = (bh & 31) << 1;

    if (tid < 128) {
        int h = h0 + (tid >> 6), w = tid & 63;
        float q = nusq[((size_t)b << 12) + h * 64 + w];
        float ncl = fmaxf(sqrtf(q), 1e-15f);
        float t = tanhf(ncl);
        float s = t / ncl;
        s_lds[tid] = s;
        lam_lds[tid] = 2.f / (1.f - s * s * q);
    }

    int wave = tid >> 6, lane = tid & 63;
    int wn = wave & 3, wm = wave >> 2;
    int lrow = lane & 15, lk = lane >> 4;

    f32x4 acc[4][4];
#pragma unroll
    for (int m = 0; m < 4; ++m)
#pragma unroll
        for (int n = 0; n < 4; ++n) acc[m][n] = (f32x4){0.f, 0.f, 0.f, 0.f};

    bf16x8 zf;
#pragma unroll
    for (int e = 0; e < 8; ++e) zf[e] = (bf16)0.0f;

    const bf16* vb = vt + (((size_t)b) << 12) * 256;
    int ldsb = wave * 1024;               // lane-linear dest within stage slice

    // stage chunk cc of A (4 rows x 64 px x 64 ch, XOR-swizzled source)
    auto stage = [&](int buf, int cc) {
#pragma unroll
        for (int it = 0; it < 4; ++it) {
            int o = it * 8192 + tid * 16;
            int r = o >> 13;
            int rem = o & 8191;
            int px = rem >> 7;
            int q = (rem >> 4) & 7;
            int qs = q ^ (px & 7);
            int hr = h0 - 1 + r;
            hr = hr < 0 ? 0 : (hr > 63 ? 63 : hr);
            const bf16* g = vb + (((size_t)(hr * 64 + px)) << 8) + cc * 64 + qs * 8;
            gload16(g, Asb + buf * 32768 + it * 8192 + ldsb);
        }
    };

    stage(0, 0);                          // prologue
    __syncthreads();                      // s_lds/lam_lds visible (also syncs)

    for (int cc = 0; cc < 4; ++cc) {
        if (cc < 3) {
            stage((cc + 1) & 1, cc + 1);  // issue next chunk into other buffer
            asm volatile("s_waitcnt vmcnt(4)" ::: "memory");  // cur chunk done
        } else {
            asm volatile("s_waitcnt vmcnt(0)" ::: "memory");
        }
        asm volatile("s_barrier" ::: "memory");   // staged data visible

        const char* Ab = Asb + ((cc & 1) << 15);
#pragma unroll
        for (int tap = 0; tap < 9; ++tap) {
            const int dh = tap / 3 - 1, dw = tap % 3 - 1;
            int hh = h0 + wm + dh;
            if ((unsigned)hh >= 64u) continue;      // wave-uniform skip
            int r = wm + dh + 1;
#pragma unroll
            for (int ks = 0; ks < 2; ++ks) {
                bf16x8 a[4];
#pragma unroll
                for (int m = 0; m < 4; ++m) {
                    int pxs = m * 16 + lrow + dw;
                    bool ok = (unsigned)pxs < 64u;
                    int pxc = ok ? pxs : 0;
                    int off = r * 8192 + pxc * 128 +
                              ((ks * 64 + lk * 16) ^ ((pxc & 7) << 4));
                    bf16x8 av = *(const bf16x8*)(Ab + off);
                    a[m] = ok ? av : zf;
                }
#pragma unroll
                for (int n = 0; n < 4; ++n) {
                    const bf16* bp = zt2 +
                        (((size_t)(tap * 8 + cc * 2 + ks) * 256) +
                         wn * 64 + n * 16 + lrow) * 32 + lk * 8;
                    bf16x8 bb = *(const bf16x8*)bp;
#pragma unroll
                    for (int m = 0; m < 4; ++m)
                        acc[m][n] = __builtin_amdgcn_mfma_f32_16x16x32_bf16(
                            a[m], bb, acc[m][n], 0, 0, 0);
                }
            }
        }
        asm volatile("s_barrier" ::: "memory");   // all reads done before restage
    }

    // ---------------- epilogue ----------------
    float znv[4], chv[4], shv[4];
#pragma unroll
    for (int n = 0; n < 4; ++n) {
        int co = wn * 64 + n * 16 + lrow;
        znv[n] = znp[co];
        chv[n] = chp[co];
        shv[n] = shp[co];
    }

#pragma unroll
    for (int m = 0; m < 4; ++m) {
#pragma unroll
        for (int r = 0; r < 4; ++r) {
            int wp = wm * 64 + m * 16 + 4 * lk + r;
            float s = s_lds[wp], lam = lam_lds[wp];
            float psum = 0.f;
#pragma unroll
            for (int n = 0; n < 4; ++n) {
                float xz = s * acc[m][n][r];
                float inner = lam * xz / znv[n] * chv[n] - (lam - 1.f) * shv[n];
                float vhp = 2.f * znv[n] * asinhf(inner);
                float w = sinhf(vhp);
                acc[m][n][r] = w;
                psum += w * w;
            }
            psum += __shfl_xor(psum, 1);
            psum += __shfl_xor(psum, 2);
            psum += __shfl_xor(psum, 4);
            psum += __shfl_xor(psum, 8);
            if (lrow == 0) red[wp][wn] = psum;
        }
    }
    __syncthreads();

    float* ob = out + (size_t)b * 256 * 4096 + (h0 + wm) * 64;
#pragma unroll
    for (int m = 0; m < 4; ++m) {
#pragma unroll
        for (int n = 0; n < 4; ++n) {
            int co = wn * 64 + n * 16 + lrow;
            f32x4 o;
#pragma unroll
            for (int r = 0; r < 4; ++r) {
                int wp = wm * 64 + m * 16 + 4 * lk + r;
                float tot = red[wp][0] + red[wp][1] + red[wp][2] + red[wp][3];
                o[r] = acc[m][n][r] / (1.f + sqrtf(1.f + tot));
            }
            *(f32x4*)(ob + (size_t)co * 4096 + m * 16 + 4 * lk) = o;
        }
    }
}

// ---------------------------------------------------------------------------
extern "C" void kernel_launch(void* const* d_in, const int* in_sizes, int n_in,
                              void* d_out, int out_size, void* d_ws, size_t ws_size,
                              hipStream_t stream) {
    const float* x = (const float*)d_in[0];   // [16,256,64,64]
    const float* z = (const float*)d_in[1];   // [2304,256]
    const float* r = (const float*)d_in[2];   // [256]
    float* out = (float*)d_out;               // [16,256,64,64]

    char* ws = (char*)d_ws;
    bf16* vt = (bf16*)ws;                         // 33,554,432 B
    float* sq = (float*)(ws + 33554432);
    float* nusq = (float*)(ws + 33816576);
    bf16* zt2 = (bf16*)(ws + 34078720);
    float* zn = (float*)(ws + 35258368);
    float* ch = (float*)(ws + 35259392);
    float* sh = (float*)(ws + 35260416);
    if (ws_size < 35261440) return;

    double bni = lgamma(128.0) + lgamma(0.5) - lgamma(128.5);
    double bn = lgamma(1152.0) + lgamma(0.5) - lgamma(1152.5);
    float Rbeta = (float)exp(bn - bni);

    k_prep_zt<<<72, 256, 0, stream>>>(z, zt2);
    k_prep_cols<<<256, 256, 0, stream>>>(z, r, zn, ch, sh);
    k_logmap<<<2048, 256, 0, stream>>>(x, (unsigned int*)vt, sq, Rbeta);
    k_boxsum<<<256, 256, 0, stream>>>(sq, nusq);
    k_hconv<<<512, 512, 0, stream>>>(vt, zt2, nusq, zn, ch, sh, out);
}

// Round 5
// 440.406 us; speedup vs baseline: 2.6250x; 2.0467x over previous
//
#include <hip/hip_runtime.h>
#include <cmath>

typedef __bf16 bf16;
typedef __bf16 bf16x8 __attribute__((ext_vector_type(8)));
typedef float f32x4 __attribute__((ext_vector_type(4)));

// B=16, C_IN=256, H=W=64, C_OUT=256, 3x3, stride 1, pad 1, CURV=1

__device__ inline void gload16(const void* g, void* l) {
    __builtin_amdgcn_global_load_lds(
        (const __attribute__((address_space(1))) unsigned int*)g,
        (__attribute__((address_space(3))) unsigned int*)l, 16, 0, 0);
}

// ---------------------------------------------------------------------------
// Weight transform: z[k=c*9+tap][co] (fp32) -> zt2[tap][kstep][co][32] (bf16)
__global__ void k_prep_zt(const float* __restrict__ z, bf16* __restrict__ zt2) {
    int blk = blockIdx.x;              // 72 = tap*8 + kstep
    int tap = blk >> 3, kstep = blk & 7;
    int co = threadIdx.x;
    bf16* o = zt2 + ((size_t)blk * 256 + co) * 32;
#pragma unroll
    for (int cj8 = 0; cj8 < 4; ++cj8) {
        bf16x8 pk;
#pragma unroll
        for (int e = 0; e < 8; ++e) {
            int c = kstep * 32 + cj8 * 8 + e;
            pk[e] = (bf16)z[(size_t)(c * 9 + tap) * 256 + co];
        }
        *(bf16x8*)(o + cj8 * 8) = pk;
    }
}

// Column constants
__global__ void k_prep_cols(const float* __restrict__ z, const float* __restrict__ r,
                            float* __restrict__ zn, float* __restrict__ ch,
                            float* __restrict__ sh) {
    __shared__ float red[256];
    int co = blockIdx.x, t = threadIdx.x;
    float s = 0.f;
    for (int i = 0; i < 9; ++i) {
        float v = z[(size_t)(i * 256 + t) * 256 + co];
        s += v * v;
    }
    red[t] = s;
    __syncthreads();
    for (int off = 128; off >= 1; off >>= 1) {
        if (t < off) red[t] += red[t + off];
        __syncthreads();
    }
    if (t == 0) {
        zn[co] = fmaxf(sqrtf(red[0]), 1e-15f);
        float tc = 2.f * r[co];
        ch[co] = coshf(tc);
        sh[co] = sinhf(tc);
    }
}

// ---------------------------------------------------------------------------
__global__ void k_logmap(const float* __restrict__ x, unsigned int* __restrict__ vt_u,
                         float* __restrict__ sq, float Rbeta) {
    __shared__ float tile[256][33];
    __shared__ float red[8][32];
    __shared__ float afac[32];
    int tid = threadIdx.x;
    int blk = blockIdx.x;
    int b = blk >> 7;
    int pix0 = (blk & 127) << 5;

    for (int it = 0; it < 32; ++it) {
        int c = it * 8 + (tid >> 5);
        int p = tid & 31;
        tile[c][p] = x[((size_t)b * 256 + c) * 4096 + pix0 + p];
    }
    __syncthreads();

    {
        int part = tid >> 5, p = tid & 31;
        float s = 0.f;
        for (int i = 0; i < 32; ++i) {
            float v = tile[part * 32 + i][p];
            s += v * v;
        }
        red[part][p] = s;
    }
    __syncthreads();
    if (tid < 32) {
        float n2 = 0.f;
        for (int i = 0; i < 8; ++i) n2 += red[i][tid];
        float n = sqrtf(n2);
        float nc = fmaxf(n, 1e-15f);
        float a = atanhf(fminf(nc, 0.9999999f)) / nc * Rbeta;
        afac[tid] = a;
        sq[(size_t)b * 4096 + pix0 + tid] = a * a * n2;
    }
    __syncthreads();

    for (int it = 0; it < 16; ++it) {
        int idx = it * 256 + tid;
        int p = idx >> 7;
        int cp = idx & 127;
        float a = afac[p];
        float v0 = a * tile[2 * cp][p];
        float v1 = a * tile[2 * cp + 1][p];
        union { bf16 h[2]; unsigned int u; } pk;
        pk.h[0] = (bf16)v0;
        pk.h[1] = (bf16)v1;
        vt_u[((size_t)b * 4096 + pix0 + p) * 128 + cp] = pk.u;
    }
}

__global__ void k_boxsum(const float* __restrict__ sq, float* __restrict__ nusq) {
    int idx = blockIdx.x * 256 + threadIdx.x;
    int b = idx >> 12, hw = idx & 4095, h = hw >> 6, w = hw & 63;
    const float* s = sq + ((size_t)b << 12);
    float acc = 0.f;
    for (int dh = -1; dh <= 1; ++dh) {
        int hh = h + dh;
        if ((unsigned)hh >= 64u) continue;
        for (int dw = -1; dw <= 1; ++dw) {
            int ww = w + dw;
            if ((unsigned)ww >= 64u) continue;
            acc += s[hh * 64 + ww];
        }
    }
    nusq[idx] = acc;
}

// ---------------------------------------------------------------------------
// Fused implicit-GEMM conv + hyperbolic FC epilogue.
// Block: 2 image rows (128 px) x 256 co, 16 waves (1024 thr). Wave tile
// 32 px x 64 co -> acc[2][4] = 32 VGPRs (fits the inherent 128-reg cap of a
// 16-wave block; rounds 2-4 spilled acc[4][4] at cap 128 -> 4.3 GB scratch).
// wm = wave>>2 in 0..3: row h0+(wm>>1), px half (wm&1)*32. wn = wave&3.
// K: 4 chunks of 64 ch, A double-buffered in LDS, counted vmcnt, raw barriers.
__launch_bounds__(1024)
__global__ void k_hconv(const bf16* __restrict__ vt, const bf16* __restrict__ zt2,
                        const float* __restrict__ nusq,
                        const float* __restrict__ znp, const float* __restrict__ chp,
                        const float* __restrict__ shp, float* __restrict__ out) {
    __shared__ __align__(1024) char Asb[65536];   // 2 x 32KB A buffers
    __shared__ float s_lds[128], lam_lds[128];
    __shared__ float red[128][4];

    int tid = threadIdx.x;
    int bh = blockIdx.x;                  // b*32 + rowpair
    int b = bh >> 5, h0 = (bh & 31) << 1;

    if (tid < 128) {
        int h = h0 + (tid >> 6), w = tid & 63;
        float q = nusq[((size_t)b << 12) + h * 64 + w];
        float ncl = fmaxf(sqrtf(q), 1e-15f);
        float t = tanhf(ncl);
        float s = t / ncl;
        s_lds[tid] = s;
        lam_lds[tid] = 2.f / (1.f - s * s * q);
    }

    int wave = tid >> 6, lane = tid & 63;
    int wn = wave & 3, wm = wave >> 2;    // wm 0..3
    int lrow = lane & 15, lk = lane >> 4;
    int hloc = wm >> 1;                   // local image row 0/1
    int pxh = (wm & 1) << 5;              // px half base 0/32

    f32x4 acc[2][4];
#pragma unroll
    for (int m = 0; m < 2; ++m)
#pragma unroll
        for (int n = 0; n < 4; ++n) acc[m][n] = (f32x4){0.f, 0.f, 0.f, 0.f};

    bf16x8 zf;
#pragma unroll
    for (int e = 0; e < 8; ++e) zf[e] = (bf16)0.0f;

    const bf16* vb = vt + (((size_t)b) << 12) * 256;
    int ldsb = wave * 1024;               // lane-linear dest slice

    // stage chunk cc of A (4 rows x 64 px x 64 ch, XOR-swizzled source);
    // 1024 thr x 16B x 2 iters = 32 KB
    auto stage = [&](int buf, int cc) {
#pragma unroll
        for (int it = 0; it < 2; ++it) {
            int o = it * 16384 + tid * 16;
            int r = o >> 13;
            int rem = o & 8191;
            int px = rem >> 7;
            int q = (rem >> 4) & 7;
            int qs = q ^ (px & 7);
            int hr = h0 - 1 + r;
            hr = hr < 0 ? 0 : (hr > 63 ? 63 : hr);
            const bf16* g = vb + (((size_t)(hr * 64 + px)) << 8) + cc * 64 + qs * 8;
            gload16(g, Asb + buf * 32768 + it * 16384 + ldsb);
        }
    };

    stage(0, 0);                          // prologue (2 loads outstanding)
    __syncthreads();                      // s_lds/lam_lds visible (also syncs)

    for (int cc = 0; cc < 4; ++cc) {
        if (cc < 3) {
            stage((cc + 1) & 1, cc + 1);  // 2 more in flight
            asm volatile("s_waitcnt vmcnt(2)" ::: "memory");  // cur chunk done
        } else {
            asm volatile("s_waitcnt vmcnt(0)" ::: "memory");
        }
        asm volatile("s_barrier" ::: "memory");

        const char* Ab = Asb + ((cc & 1) << 15);
#pragma unroll
        for (int tap = 0; tap < 9; ++tap) {
            const int dh = tap / 3 - 1, dw = tap % 3 - 1;
            int hh = h0 + hloc + dh;
            if ((unsigned)hh >= 64u) continue;      // wave-uniform skip
            int r = hloc + dh + 1;
#pragma unroll
            for (int ks = 0; ks < 2; ++ks) {
                bf16x8 a[2];
#pragma unroll
                for (int m = 0; m < 2; ++m) {
                    int pxs = pxh + m * 16 + lrow + dw;
                    bool ok = (unsigned)pxs < 64u;
                    int pxc = ok ? pxs : 0;
                    int off = r * 8192 + pxc * 128 +
                              ((ks * 64 + lk * 16) ^ ((pxc & 7) << 4));
                    bf16x8 av = *(const bf16x8*)(Ab + off);
                    a[m] = ok ? av : zf;
                }
#pragma unroll
                for (int n = 0; n < 4; ++n) {
                    const bf16* bp = zt2 +
                        (((size_t)(tap * 8 + cc * 2 + ks) * 256) +
                         wn * 64 + n * 16 + lrow) * 32 + lk * 8;
                    bf16x8 bb = *(const bf16x8*)bp;
#pragma unroll
                    for (int m = 0; m < 2; ++m)
                        acc[m][n] = __builtin_amdgcn_mfma_f32_16x16x32_bf16(
                            a[m], bb, acc[m][n], 0, 0, 0);
                }
            }
        }
        asm volatile("s_barrier" ::: "memory");   // reads done before restage
    }

    // ---------------- epilogue ----------------
    float znv[4], chv[4], shv[4];
#pragma unroll
    for (int n = 0; n < 4; ++n) {
        int co = wn * 64 + n * 16 + lrow;
        znv[n] = znp[co];
        chv[n] = chp[co];
        shv[n] = shp[co];
    }

#pragma unroll
    for (int m = 0; m < 2; ++m) {
#pragma unroll
        for (int r = 0; r < 4; ++r) {
            int wp = wm * 32 + m * 16 + 4 * lk + r;   // block-local px slot
            float s = s_lds[wp], lam = lam_lds[wp];
            float psum = 0.f;
#pragma unroll
            for (int n = 0; n < 4; ++n) {
                float xz = s * acc[m][n][r];
                float inner = lam * xz / znv[n] * chv[n] - (lam - 1.f) * shv[n];
                float vhp = 2.f * znv[n] * asinhf(inner);
                float w = sinhf(vhp);
                acc[m][n][r] = w;
                psum += w * w;
            }
            psum += __shfl_xor(psum, 1);
            psum += __shfl_xor(psum, 2);
            psum += __shfl_xor(psum, 4);
            psum += __shfl_xor(psum, 8);
            if (lrow == 0) red[wp][wn] = psum;
        }
    }
    __syncthreads();

    float* ob = out + (size_t)b * 256 * 4096 + (h0 + hloc) * 64 + pxh;
#pragma unroll
    for (int m = 0; m < 2; ++m) {
#pragma unroll
        for (int n = 0; n < 4; ++n) {
            int co = wn * 64 + n * 16 + lrow;
            f32x4 o;
#pragma unroll
            for (int r = 0; r < 4; ++r) {
                int wp = wm * 32 + m * 16 + 4 * lk + r;
                float tot = red[wp][0] + red[wp][1] + red[wp][2] + red[wp][3];
                o[r] = acc[m][n][r] / (1.f + sqrtf(1.f + tot));
            }
            *(f32x4*)(ob + (size_t)co * 4096 + m * 16 + 4 * lk) = o;
        }
    }
}

// ---------------------------------------------------------------------------
extern "C" void kernel_launch(void* const* d_in, const int* in_sizes, int n_in,
                              void* d_out, int out_size, void* d_ws, size_t ws_size,
                              hipStream_t stream) {
    const float* x = (const float*)d_in[0];   // [16,256,64,64]
    const float* z = (const float*)d_in[1];   // [2304,256]
    const float* r = (const float*)d_in[2];   // [256]
    float* out = (float*)d_out;               // [16,256,64,64]

    char* ws = (char*)d_ws;
    bf16* vt = (bf16*)ws;                         // 33,554,432 B
    float* sq = (float*)(ws + 33554432);
    float* nusq = (float*)(ws + 33816576);
    bf16* zt2 = (bf16*)(ws + 34078720);
    float* zn = (float*)(ws + 35258368);
    float* ch = (float*)(ws + 35259392);
    float* sh = (float*)(ws + 35260416);
    if (ws_size < 35261440) return;

    double bni = lgamma(128.0) + lgamma(0.5) - lgamma(128.5);
    double bn = lgamma(1152.0) + lgamma(0.5) - lgamma(1152.5);
    float Rbeta = (float)exp(bn - bni);

    k_prep_zt<<<72, 256, 0, stream>>>(z, zt2);
    k_prep_cols<<<256, 256, 0, stream>>>(z, r, zn, ch, sh);
    k_logmap<<<2048, 256, 0, stream>>>(x, (unsigned int*)vt, sq, Rbeta);
    k_boxsum<<<256, 256, 0, stream>>>(sq, nusq);
    k_hconv<<<512, 1024, 0, stream>>>(vt, zt2, nusq, zn, ch, sh, out);
}

// Round 6
// 233.750 us; speedup vs baseline: 4.9458x; 1.8841x over previous
//
#include <hip/hip_runtime.h>
#include <cmath>

typedef __bf16 bf16;
typedef __bf16 bf16x8 __attribute__((ext_vector_type(8)));
typedef float f32x4 __attribute__((ext_vector_type(4)));

// B=16, C_IN=256, H=W=64, C_OUT=256, 3x3, stride 1, pad 1, CURV=1

__device__ inline void gload16(const void* g, void* l) {
    __builtin_amdgcn_global_load_lds(
        (const __attribute__((address_space(1))) unsigned int*)g,
        (__attribute__((address_space(3))) unsigned int*)l, 16, 0, 0);
}

// ---------------------------------------------------------------------------
// Weight transform: z[k=c*9+tap][co] (fp32) -> zt3[s=cc*9+tap][co][64ch] bf16,
// granule-swizzled: granule g of row co holds channels cc*64 + (g^(co&7))*8.
// 32 KB per stage s; staging into LDS is then a linear copy.
__global__ void k_prep_zt(const float* __restrict__ z, bf16* __restrict__ zt3) {
    int blk = blockIdx.x;              // 36 = cc*9 + tap
    int cc = blk / 9, tap = blk % 9;
    int co = threadIdx.x;
    bf16* o = zt3 + ((size_t)blk * 256 + co) * 64;
#pragma unroll
    for (int g = 0; g < 8; ++g) {
        int gs = g ^ (co & 7);
        bf16x8 pk;
#pragma unroll
        for (int e = 0; e < 8; ++e) {
            int c = cc * 64 + gs * 8 + e;
            pk[e] = (bf16)z[(size_t)(c * 9 + tap) * 256 + co];
        }
        *(bf16x8*)(o + g * 8) = pk;
    }
}

// Column constants
__global__ void k_prep_cols(const float* __restrict__ z, const float* __restrict__ r,
                            float* __restrict__ zn, float* __restrict__ ch,
                            float* __restrict__ sh) {
    __shared__ float red[256];
    int co = blockIdx.x, t = threadIdx.x;
    float s = 0.f;
    for (int i = 0; i < 9; ++i) {
        float v = z[(size_t)(i * 256 + t) * 256 + co];
        s += v * v;
    }
    red[t] = s;
    __syncthreads();
    for (int off = 128; off >= 1; off >>= 1) {
        if (t < off) red[t] += red[t + off];
        __syncthreads();
    }
    if (t == 0) {
        zn[co] = fmaxf(sqrtf(red[0]), 1e-15f);
        float tc = 2.f * r[co];
        ch[co] = coshf(tc);
        sh[co] = sinhf(tc);
    }
}

// ---------------------------------------------------------------------------
__global__ void k_logmap(const float* __restrict__ x, unsigned int* __restrict__ vt_u,
                         float* __restrict__ sq, float Rbeta) {
    __shared__ float tile[256][33];
    __shared__ float red[8][32];
    __shared__ float afac[32];
    int tid = threadIdx.x;
    int blk = blockIdx.x;
    int b = blk >> 7;
    int pix0 = (blk & 127) << 5;

    for (int it = 0; it < 32; ++it) {
        int c = it * 8 + (tid >> 5);
        int p = tid & 31;
        tile[c][p] = x[((size_t)b * 256 + c) * 4096 + pix0 + p];
    }
    __syncthreads();

    {
        int part = tid >> 5, p = tid & 31;
        float s = 0.f;
        for (int i = 0; i < 32; ++i) {
            float v = tile[part * 32 + i][p];
            s += v * v;
        }
        red[part][p] = s;
    }
    __syncthreads();
    if (tid < 32) {
        float n2 = 0.f;
        for (int i = 0; i < 8; ++i) n2 += red[i][tid];
        float n = sqrtf(n2);
        float nc = fmaxf(n, 1e-15f);
        float a = atanhf(fminf(nc, 0.9999999f)) / nc * Rbeta;
        afac[tid] = a;
        sq[(size_t)b * 4096 + pix0 + tid] = a * a * n2;
    }
    __syncthreads();

    for (int it = 0; it < 16; ++it) {
        int idx = it * 256 + tid;
        int p = idx >> 7;
        int cp = idx & 127;
        float a = afac[p];
        float v0 = a * tile[2 * cp][p];
        float v1 = a * tile[2 * cp + 1][p];
        union { bf16 h[2]; unsigned int u; } pk;
        pk.h[0] = (bf16)v0;
        pk.h[1] = (bf16)v1;
        vt_u[((size_t)b * 4096 + pix0 + p) * 128 + cp] = pk.u;
    }
}

__global__ void k_boxsum(const float* __restrict__ sq, float* __restrict__ nusq) {
    int idx = blockIdx.x * 256 + threadIdx.x;
    int b = idx >> 12, hw = idx & 4095, h = hw >> 6, w = hw & 63;
    const float* s = sq + ((size_t)b << 12);
    float acc = 0.f;
    for (int dh = -1; dh <= 1; ++dh) {
        int hh = h + dh;
        if ((unsigned)hh >= 64u) continue;
        for (int dw = -1; dw <= 1; ++dw) {
            int ww = w + dw;
            if ((unsigned)ww >= 64u) continue;
            acc += s[hh * 64 + ww];
        }
    }
    nusq[idx] = acc;
}

// ---------------------------------------------------------------------------
// Fused implicit-GEMM conv + hyperbolic FC epilogue. Both operands LDS-staged.
// Block: 2 image rows (128 px) x 256 co, 16 waves. Wave tile 32 px x 64 co
// (acc[2][4] = 32 regs -- no spill at the 16-wave cap; rounds 2-4 lesson).
// Flattened stage loop s = cc*9+tap (36 stages): B[s] (32 KB) double-buffered
// per stage, A[cc] (32 KB) double-buffered per chunk; counted vmcnt keeps the
// next stage's loads in flight across raw s_barriers (T3/T4).
__launch_bounds__(1024)
__global__ void k_hconv(const bf16* __restrict__ vt, const bf16* __restrict__ zt3,
                        const float* __restrict__ nusq,
                        const float* __restrict__ znp, const float* __restrict__ chp,
                        const float* __restrict__ shp, float* __restrict__ out) {
    __shared__ __align__(1024) char Asb[65536];   // 2 x 32KB A (swizzled)
    __shared__ __align__(1024) char Bsb[65536];   // 2 x 32KB B (swizzled)
    __shared__ float s_lds[128], lam_lds[128];
    __shared__ float red[128][4];

    int tid = threadIdx.x;
    int bid = blockIdx.x;
    int bh = ((bid & 7) << 6) | (bid >> 3);   // XCD-bijective: 512 = 8 x 64
    int b = bh >> 5, h0 = (bh & 31) << 1;

    if (tid < 128) {
        int h = h0 + (tid >> 6), w = tid & 63;
        float q = nusq[((size_t)b << 12) + h * 64 + w];
        float ncl = fmaxf(sqrtf(q), 1e-15f);
        float t = tanhf(ncl);
        float s = t / ncl;
        s_lds[tid] = s;
        lam_lds[tid] = 2.f / (1.f - s * s * q);
    }

    int wave = tid >> 6, lane = tid & 63;
    int wn = wave & 3, wm = wave >> 2;    // wm 0..3
    int lrow = lane & 15, lk = lane >> 4;
    int hloc = wm >> 1;                   // local image row 0/1
    int pxh = (wm & 1) << 5;              // px half base 0/32

    f32x4 acc[2][4];
#pragma unroll
    for (int m = 0; m < 2; ++m)
#pragma unroll
        for (int n = 0; n < 4; ++n) acc[m][n] = (f32x4){0.f, 0.f, 0.f, 0.f};

    bf16x8 zf;
#pragma unroll
    for (int e = 0; e < 8; ++e) zf[e] = (bf16)0.0f;

    const bf16* vb = vt + (((size_t)b) << 12) * 256;
    int ldsb = wave * 1024;

    // stage A chunk cc (4 rows x 64 px x 64 ch, XOR-swizzled source): 2 loads
    auto stageA = [&](int buf, int cc) {
#pragma unroll
        for (int it = 0; it < 2; ++it) {
            int o = it * 16384 + tid * 16;
            int r = o >> 13;
            int rem = o & 8191;
            int px = rem >> 7;
            int q = (rem >> 4) & 7;
            int qs = q ^ (px & 7);
            int hr = h0 - 1 + r;
            hr = hr < 0 ? 0 : (hr > 63 ? 63 : hr);
            const bf16* g = vb + (((size_t)(hr * 64 + px)) << 8) + cc * 64 + qs * 8;
            gload16(g, Asb + buf * 32768 + it * 16384 + ldsb);
        }
    };
    // stage B stage s (256 co x 64 ch, pre-swizzled in zt3 -> linear copy)
    auto stageB = [&](int buf, int s) {
        const char* src = (const char*)zt3 + (size_t)s * 32768;
#pragma unroll
        for (int it = 0; it < 2; ++it) {
            int o = (wave * 2 + it) * 1024;
            gload16(src + o + lane * 16, Bsb + buf * 32768 + o);
        }
    };

    stageA(0, 0);
    stageB(0, 0);
    __syncthreads();                      // drain prologue; s_lds visible

#pragma unroll
    for (int cc = 0; cc < 4; ++cc) {
#pragma unroll
        for (int tap = 0; tap < 9; ++tap) {
            const int s = cc * 9 + tap;
            if (s < 35) stageB((s + 1) & 1, s + 1);
            if (tap == 0 && cc < 3) {
                stageA((cc + 1) & 1, cc + 1);
                asm volatile("s_waitcnt vmcnt(4)" ::: "memory");
            } else if (s < 35) {
                asm volatile("s_waitcnt vmcnt(2)" ::: "memory");
            } else {
                asm volatile("s_waitcnt vmcnt(0)" ::: "memory");
            }
            asm volatile("s_barrier" ::: "memory");   // stage-s data ready

            const int dh = tap / 3 - 1, dw = tap % 3 - 1;
            int hh = h0 + hloc + dh;
            if ((unsigned)hh < 64u) {                 // wave-uniform
                const char* Ab = Asb + ((cc & 1) << 15);
                const char* Bb = Bsb + ((s & 1) << 15);
                int r = hloc + dh + 1;
#pragma unroll
                for (int ks = 0; ks < 2; ++ks) {
                    bf16x8 a[2];
#pragma unroll
                    for (int m = 0; m < 2; ++m) {
                        int pxs = pxh + m * 16 + lrow + dw;
                        bool ok = (unsigned)pxs < 64u;
                        int pxc = ok ? pxs : 0;
                        int off = r * 8192 + pxc * 128 +
                                  ((ks * 64 + lk * 16) ^ ((pxc & 7) << 4));
                        bf16x8 av = *(const bf16x8*)(Ab + off);
                        a[m] = ok ? av : zf;
                    }
                    bf16x8 bb[4];
#pragma unroll
                    for (int n = 0; n < 4; ++n) {
                        int co = wn * 64 + n * 16 + lrow;
                        int off = co * 128 +
                                  ((ks * 64 + lk * 16) ^ ((lrow & 7) << 4));
                        bb[n] = *(const bf16x8*)(Bb + off);
                    }
                    __builtin_amdgcn_s_setprio(1);
#pragma unroll
                    for (int n = 0; n < 4; ++n)
#pragma unroll
                        for (int m = 0; m < 2; ++m)
                            acc[m][n] = __builtin_amdgcn_mfma_f32_16x16x32_bf16(
                                a[m], bb[n], acc[m][n], 0, 0, 0);
                    __builtin_amdgcn_s_setprio(0);
                }
            }
            asm volatile("s_barrier" ::: "memory");   // reads done pre-restage
        }
    }

    // ---------------- epilogue ----------------
    float znv[4], chv[4], shv[4];
#pragma unroll
    for (int n = 0; n < 4; ++n) {
        int co = wn * 64 + n * 16 + lrow;
        znv[n] = znp[co];
        chv[n] = chp[co];
        shv[n] = shp[co];
    }

#pragma unroll
    for (int m = 0; m < 2; ++m) {
#pragma unroll
        for (int r = 0; r < 4; ++r) {
            int wp = wm * 32 + m * 16 + 4 * lk + r;   // block-local px slot
            float s = s_lds[wp], lam = lam_lds[wp];
            float psum = 0.f;
#pragma unroll
            for (int n = 0; n < 4; ++n) {
                float xz = s * acc[m][n][r];
                float inner = lam * xz / znv[n] * chv[n] - (lam - 1.f) * shv[n];
                float vhp = 2.f * znv[n] * asinhf(inner);
                float w = sinhf(vhp);
                acc[m][n][r] = w;
                psum += w * w;
            }
            psum += __shfl_xor(psum, 1);
            psum += __shfl_xor(psum, 2);
            psum += __shfl_xor(psum, 4);
            psum += __shfl_xor(psum, 8);
            if (lrow == 0) red[wp][wn] = psum;
        }
    }
    __syncthreads();

    float* ob = out + (size_t)b * 256 * 4096 + (h0 + hloc) * 64 + pxh;
#pragma unroll
    for (int m = 0; m < 2; ++m) {
#pragma unroll
        for (int n = 0; n < 4; ++n) {
            int co = wn * 64 + n * 16 + lrow;
            f32x4 o;
#pragma unroll
            for (int r = 0; r < 4; ++r) {
                int wp = wm * 32 + m * 16 + 4 * lk + r;
                float tot = red[wp][0] + red[wp][1] + red[wp][2] + red[wp][3];
                o[r] = acc[m][n][r] / (1.f + sqrtf(1.f + tot));
            }
            *(f32x4*)(ob + (size_t)co * 4096 + m * 16 + 4 * lk) = o;
        }
    }
}

// ---------------------------------------------------------------------------
extern "C" void kernel_launch(void* const* d_in, const int* in_sizes, int n_in,
                              void* d_out, int out_size, void* d_ws, size_t ws_size,
                              hipStream_t stream) {
    const float* x = (const float*)d_in[0];   // [16,256,64,64]
    const float* z = (const float*)d_in[1];   // [2304,256]
    const float* r = (const float*)d_in[2];   // [256]
    float* out = (float*)d_out;               // [16,256,64,64]

    char* ws = (char*)d_ws;
    bf16* vt = (bf16*)ws;                         // 33,554,432 B
    float* sq = (float*)(ws + 33554432);
    float* nusq = (float*)(ws + 33816576);
    bf16* zt3 = (bf16*)(ws + 34078720);           // 36*32KB = 1,179,648 B
    float* zn = (float*)(ws + 35258368);
    float* ch = (float*)(ws + 35259392);
    float* sh = (float*)(ws + 35260416);
    if (ws_size < 35261440) return;

    double bni = lgamma(128.0) + lgamma(0.5) - lgamma(128.5);
    double bn = lgamma(1152.0) + lgamma(0.5) - lgamma(1152.5);
    float Rbeta = (float)exp(bn - bni);

    k_prep_zt<<<36, 256, 0, stream>>>(z, zt3);
    k_prep_cols<<<256, 256, 0, stream>>>(z, r, zn, ch, sh);
    k_logmap<<<2048, 256, 0, stream>>>(x, (unsigned int*)vt, sq, Rbeta);
    k_boxsum<<<256, 256, 0, stream>>>(sq, nusq);
    k_hconv<<<512, 1024, 0, stream>>>(vt, zt3, nusq, zn, ch, sh, out);
}